// Round 8
// baseline (79.085 us; speedup 1.0000x reference)
//
#include <hip/hip_runtime.h>

#define DIM 64
#define HW 4096          // 64*64
#define NELEM 8388608.0f // 32*64*4096
#define NBLK 1024        // 128-col tiles

typedef __attribute__((ext_vector_type(8))) short short8;   // 8 x bf16
typedef __attribute__((ext_vector_type(4))) float f32x4;
typedef __attribute__((ext_vector_type(2))) float f32x2;

__device__ __forceinline__ unsigned short f2bf(float f) {
  unsigned int u = __builtin_bit_cast(unsigned int, f);
  u += 0x7fffu + ((u >> 16) & 1u);            // round-to-nearest-even
  return (unsigned short)(u >> 16);
}

__device__ __forceinline__ float wave_sum(float v) {
  #pragma unroll
  for (int off = 32; off >= 1; off >>= 1) v += __shfl_xor(v, off);
  return v;
}

// ws layout (bytes):
//  [0,     4096)  per-block partial sum(x^2)      (1024 floats)
//  [4096,  8192)  per-block partial sum(min d2')  (1024 floats)

// ---- main: 1024 blocks x 4 waves; 128-col tile; codes split across waves --
// R8: vq_prep FUSED (launch-count test, R2 redone without spills).
// Phase order caps VGPR pressure: (1) issue X nt-loads; (2) convert this
// wave's 128 codes CB->bf16(-2c) areg[8][2] (64 VGPR) + fp32 ||c||^2 via
// 2x shfl_xor, all under X-load latency; (3) broadcast cnq[8] (width-16
// shfl); (4) PACKX (v regs die before bfrag born); (5) R1's proven compute
// body with areg/cnq replacing aFg/cng loads.  launch_bounds(256,3): 170-
// VGPR budget (peak ~150 live), 18KB LDS -> 3 blocks/CU.
// NO atomics/fences (same-addr device atomics ~100us convoy, prev session).
__global__ __launch_bounds__(256, 3)
void vq_main(const float* __restrict__ X, const float* __restrict__ CB,
             float* __restrict__ out,
             float* __restrict__ pA, float* __restrict__ pB) {
  __shared__ __align__(16) unsigned short XF[16 * 64 * 8]; // 16 KB frag-order
  __shared__ float mW[4][128];                // per-wave packed mins per col
  __shared__ float red[8];

  const int t   = threadIdx.x;
  const int bid = blockIdx.x;
  // XCD-chunked swizzle: XCD x owns logical blocks [x*128,(x+1)*128)
  const int L   = ((bid & 7) << 7) | (bid >> 3);
  const int n   = L >> 5;                     // image (32 tiles of 128 cols)
  const int hw0 = (L & 31) << 7;              // 128-col tile
  const int wv  = t >> 6, lane = t & 63;
  const int g   = lane >> 4, lcol = lane & 15;

  const float* Xg = X + n * (DIM * HW) + hw0;

  // ---- (1) issue X loads first (HBM, nontemporal) ------------------------
  const int db8 = t >> 5;                     // 0..7
  const int cp  = t & 31;                     // 0..31
  const int kss = db8 >> 2, gs = db8 & 3;
  f32x2 v[2][8];
  #pragma unroll
  for (int h = 0; h < 2; ++h)
    #pragma unroll
    for (int j = 0; j < 8; ++j)
      v[h][j] = __builtin_nontemporal_load(
          (const f32x2*)(Xg + (db8 * 8 + j) * HW + h * 64 + cp * 2));
  __builtin_amdgcn_sched_barrier(0);          // keep X loads issued first

  // ---- (2) this wave's 128 codes: CB fp32 -> bf16(-2c) in regs -----------
  // lane holds code = chunk*16+lcol, dims ks*32+g*8..+7  (== old aFg slot)
  short8 areg[8][2];
  float cnv[8];
  #pragma unroll 2
  for (int i = 0; i < 8; ++i) {
    const int code = (wv * 8 + i) * 16 + lcol;
    float pc = 0.f;
    #pragma unroll
    for (int ks = 0; ks < 2; ++ks) {
      const float* cpp = CB + code * DIM + ks * 32 + g * 8;
      float4 u0 = *(const float4*)cpp;
      float4 u1 = *(const float4*)(cpp + 4);
      pc += u0.x*u0.x + u0.y*u0.y + u0.z*u0.z + u0.w*u0.w
          + u1.x*u1.x + u1.y*u1.y + u1.z*u1.z + u1.w*u1.w;
      short8 p;
      p[0]=(short)f2bf(-2.f*u0.x); p[1]=(short)f2bf(-2.f*u0.y);
      p[2]=(short)f2bf(-2.f*u0.z); p[3]=(short)f2bf(-2.f*u0.w);
      p[4]=(short)f2bf(-2.f*u1.x); p[5]=(short)f2bf(-2.f*u1.y);
      p[6]=(short)f2bf(-2.f*u1.z); p[7]=(short)f2bf(-2.f*u1.w);
      areg[i][ks] = p;
    }
    pc += __shfl_xor(pc, 16);                 // 4 g-groups, same code
    pc += __shfl_xor(pc, 32);                 // -> exact fp32 ||c||^2
    cnv[i] = pc;
  }

  // ---- (3) broadcast: cnq[i][r] = ||c_{codebase+r}||^2 -------------------
  f32x4 cnq[8];
  #pragma unroll
  for (int i = 0; i < 8; ++i) {
    #pragma unroll
    for (int r = 0; r < 4; ++r)
      cnq[i][r] = __shfl(cnv[i], g * 4 + r, 16);
  }

  // ---- (4) consume X: sum(x^2) + bf16 pack into fragment-order LDS -------
  float sx2 = 0.f;
  #pragma unroll
  for (int h = 0; h < 2; ++h)
    #pragma unroll
    for (int j = 0; j < 8; ++j)
      sx2 += v[h][j].x * v[h][j].x + v[h][j].y * v[h][j].y;
  #pragma unroll
  for (int h = 0; h < 2; ++h) {
    #pragma unroll
    for (int ci = 0; ci < 2; ++ci) {
      const int cl   = cp * 2 + ci;           // 0..63 within half
      const int cb   = h * 4 + (cl >> 4);     // 0..7 col-block
      const int slot = (cb * 2 + kss) * 64 + gs * 16 + (cl & 15);
      const int swz  = slot ^ ((slot >> 3) & 7);
      short8 w;
      #pragma unroll
      for (int j = 0; j < 8; ++j)
        w[j] = (short)f2bf(ci ? v[h][j].y : v[h][j].x);
      *(short8*)&XF[swz * 8] = w;
    }
  }
  __syncthreads();

  // ---- (5) compute: R1's proven body, A/cn register-sourced --------------
  const int swzl = lane ^ ((lane >> 3) & 7);
  float m1[8];
  #pragma unroll
  for (int cb = 0; cb < 8; ++cb) m1[cb] = 3.0e38f;

  #pragma unroll
  for (int h = 0; h < 2; ++h) {
    short8 bfrag[4][2];                       // half-resident (32 VGPR)
    #pragma unroll
    for (int cb2 = 0; cb2 < 4; ++cb2)
      #pragma unroll
      for (int ks = 0; ks < 2; ++ks)
        bfrag[cb2][ks] =
            *(const short8*)&XF[(((h * 4 + cb2) * 2 + ks) * 64 + swzl) * 8];

    #pragma unroll 2
    for (int i = 0; i < 8; ++i) {
      const int codebase = (wv * 8 + i) * 16 + g * 4;
      #pragma unroll
      for (int cb2 = 0; cb2 < 4; ++cb2) {
        f32x4 acc = cnq[i];
        acc = __builtin_amdgcn_mfma_f32_16x16x32_bf16(areg[i][0], bfrag[cb2][0], acc, 0, 0, 0);
        acc = __builtin_amdgcn_mfma_f32_16x16x32_bf16(areg[i][1], bfrag[cb2][1], acc, 0, 0, 0);
        #pragma unroll
        for (int r = 0; r < 4; ++r) {
          unsigned int vb = __builtin_bit_cast(unsigned int, acc[r]);
          vb = (vb & 0xFFFFFE00u) | ((unsigned)(codebase + r) & 0x1FFu);
          m1[h * 4 + cb2] = fminf(m1[h * 4 + cb2], __builtin_bit_cast(float, vb));
        }
      }
    }
  }

  // combine lane-groups (disjoint code subsets, same col)
  #pragma unroll
  for (int cb = 0; cb < 8; ++cb) {
    m1[cb] = fminf(m1[cb], __shfl_xor(m1[cb], 16));
    m1[cb] = fminf(m1[cb], __shfl_xor(m1[cb], 32));
    if (g == 0) mW[wv][cb * 16 + lcol] = m1[cb];
  }
  __syncthreads();

  // ---- final per-col argmin + epilogue, two 64-col passes ----------------
  float msum = 0.f;
  #pragma unroll
  for (int h = 0; h < 2; ++h) {
    const int c = h * 64 + lane;
    const float p = fminf(fminf(mW[0][c], mW[1][c]),
                          fminf(mW[2][c], mW[3][c]));
    const unsigned int b = __builtin_bit_cast(unsigned int, p);
    const int k = (int)(b & 511u);
    msum += __builtin_bit_cast(float, b & 0xFFFFFE00u);

    const float* cq = CB + k * DIM + wv * 16; // L2-hot gather
    float* op = out + 1 + n * (DIM * HW) + hw0 + c;
    #pragma unroll
    for (int i = 0; i < 4; ++i) {
      float4 u = *(const float4*)(cq + i * 4);
      op[(wv*16 + i*4 + 0) * HW] = u.x;
      op[(wv*16 + i*4 + 1) * HW] = u.y;
      op[(wv*16 + i*4 + 2) * HW] = u.z;
      op[(wv*16 + i*4 + 3) * HW] = u.w;
    }
  }

  // ---- loss partials (no atomics; vq_fin reduces) ----
  float w1 = wave_sum(sx2);
  if (lane == 0) red[wv] = w1;
  if (wv == 0) {
    float w2 = wave_sum(msum);                // each col counted once
    if (lane == 0) red[4] = w2;
  }
  __syncthreads();
  if (t == 0) {
    pA[bid] = red[0] + red[1] + red[2] + red[3];
    pB[bid] = red[4];
  }
}

__global__ void vq_fin(const float* __restrict__ pA,
                       const float* __restrict__ pB,
                       float* __restrict__ out) {
  const int t = threadIdx.x;                  // 512 threads, 1024 partials
  f32x2 a = *(const f32x2*)&pA[t * 2];
  f32x2 c = *(const f32x2*)&pB[t * 2];
  float v = a.x + a.y + c.x + c.y;
  v = wave_sum(v);
  __shared__ float r[8];
  if ((t & 63) == 0) r[t >> 6] = v;
  __syncthreads();
  if (t == 0) {
    float s = 0.f;
    #pragma unroll
    for (int i = 0; i < 8; ++i) s += r[i];
    out[0] = 1.25f * s * (1.0f / NELEM);
  }
}

extern "C" void kernel_launch(void* const* d_in, const int* in_sizes, int n_in,
                              void* d_out, int out_size, void* d_ws, size_t ws_size,
                              hipStream_t stream) {
  const float* X  = (const float*)d_in[0];   // [32,64,64,64] fp32
  const float* CB = (const float*)d_in[1];   // [512,64] fp32
  float* out = (float*)d_out;                // [0]=loss, [1..]=quantized_st
  char* ws = (char*)d_ws;
  float* pA = (float*)ws;
  float* pB = (float*)(ws + 4096);
  (void)in_sizes; (void)n_in; (void)out_size; (void)ws_size;

  vq_main<<<NBLK, 256, 0, stream>>>(X, CB, out, pA, pB);
  vq_fin<<<1, 512, 0, stream>>>(pA, pB, out);
}